// Round 10
// baseline (2515.570 us; speedup 1.0000x reference)
//
#include <hip/hip_runtime.h>
#include <hip/hip_fp16.h>

#define B_ 256
#define T_ 4096
#define I_ 64
#define H_ 36
#define G_ 144   // 4*H
#define O_ 2
#define TS 32            // timesteps per LDS tile
#define NTILES (T_ / TS) // 128
#define UNROLL 8

typedef __fp16 h2 __attribute__((ext_vector_type(2)));

__device__ __forceinline__ float fsigmoid(float x) {
  float e = __builtin_amdgcn_exp2f(x * -1.442695040888963f);
  return __builtin_amdgcn_rcpf(1.0f + e);
}
__device__ __forceinline__ float ftanh(float x) {
  float e = __builtin_amdgcn_exp2f(x * 2.885390081777926f);
  return 1.0f - 2.0f * __builtin_amdgcn_rcpf(1.0f + e);
}
__device__ __forceinline__ h2 pack2(float lo, float hi) {
  return __builtin_amdgcn_cvt_pkrtz(lo, hi);
}
__device__ __forceinline__ float fdot2(h2 a, h2 b, float c) {
  return __builtin_amdgcn_fdot2(a, b, c, false);
}

// broadcast helper: build (h[j], h[j+1]) half2 on even lanes, no DS ops.
__device__ __forceinline__ int pack_pair_dpp(float hj) {
  int hn_i = __builtin_amdgcn_update_dpp(0, __float_as_int(hj), 0xF5, 0xF, 0xF, true);
  float hn = __int_as_float(hn_i);
  return __builtin_bit_cast(int, pack2(hj, hn));
}

// ---------------- fully fused LSTM: wave0 = recurrence, waves1-2 = xg gemm + stage ----------------
__global__ __launch_bounds__(192, 1) void lstm_fused(
    const float* __restrict__ x,      // [T][B][64]
    const float* __restrict__ W_ih,   // [144][64]
    const float* __restrict__ W_hh,   // [144][36]
    const float* __restrict__ b_ih,   // [144]
    const float* __restrict__ b_hh,   // [144]
    const float* __restrict__ W_out,  // [2][36]
    const float* __restrict__ b_out,  // [2]
    float* __restrict__ y)            // [T][B][2] fp32
{
  __shared__ float Wlds[G_ * I_];     // W_ih fp32, 36 KiB
  __shared__ float bias[G_];          // b_ih+b_hh
  __shared__ uint2 buf[2][TS * H_];   // xg tiles, fp16-packed (i,f),(g,o): 18.4 KiB
  __shared__ float ybuf[2][TS][O_];   // staged y pairs

  const int b = blockIdx.x;
  const int tid = threadIdx.x;
  const int wv = tid >> 6;            // 0 = consumer, 1/2 = producers
  const int j = tid & 63;

  // ---- stage W_ih + bias into LDS (all 192 threads) ----
  {
    const float4* src = (const float4*)W_ih;
    float4* dst = (float4*)Wlds;
    for (int i = tid; i < G_ * I_ / 4; i += 192) dst[i] = src[i];
    for (int i = tid; i < G_; i += 192) bias[i] = b_ih[i] + b_hh[i];
  }

  // ---- consumer init (wave 0): W_hh / W_out fp16 pairs in registers ----
  h2 wA[36], wB[36];                  // wA[0..17]=i pairs, wA[18..35]=f; wB: g,o
  float hj = 0.0f, cj = 0.0f, yb = 0.0f;
  int jj = 0;
  if (wv == 0) {
    if (j < H_) {
#pragma unroll
      for (int t = 0; t < 18; t++) {
        wA[t]      = pack2(W_hh[j * H_ + 2 * t],            W_hh[j * H_ + 2 * t + 1]);
        wA[18 + t] = pack2(W_hh[(j + H_) * H_ + 2 * t],     W_hh[(j + H_) * H_ + 2 * t + 1]);
        wB[t]      = pack2(W_hh[(j + 2 * H_) * H_ + 2 * t], W_hh[(j + 2 * H_) * H_ + 2 * t + 1]);
        wB[18 + t] = pack2(W_hh[(j + 3 * H_) * H_ + 2 * t], W_hh[(j + 3 * H_) * H_ + 2 * t + 1]);
      }
    } else if (j < H_ + O_) {
      const int o = j - H_;
#pragma unroll
      for (int t = 0; t < 18; t++) {
        wA[t] = pack2(W_out[o * H_ + 2 * t], W_out[o * H_ + 2 * t + 1]);
        wA[18 + t] = pack2(0.f, 0.f);
        wB[t] = pack2(0.f, 0.f); wB[18 + t] = pack2(0.f, 0.f);
      }
      yb = b_out[o];
    } else {
#pragma unroll
      for (int k = 0; k < H_; k++) { wA[k] = pack2(0.f, 0.f); wB[k] = pack2(0.f, 0.f); }
    }
    jj = (j < H_) ? j : 0;
  }

  // ---- producer lane mapping: step = (wv-1)*16 + (lane>>2), quarter = lane&3 ----
  const int ps = ((wv - 1) << 4) + (j >> 2);   // 0..31 (valid for wv>=1)
  const int pq = j & 3;                        // units pq*9 .. pq*9+8

  auto produce = [&](int tt, uint2* dstbuf) {
    const float4* xrow = (const float4*)(x + ((size_t)(tt * TS + ps) * B_ + b) * I_);
    float4 xv[16];
#pragma unroll
    for (int c = 0; c < 16; ++c) xv[c] = xrow[c];
#pragma unroll
    for (int m = 0; m < 9; ++m) {
      const int u = pq * 9 + m;
      float a[4];
#pragma unroll
      for (int Gg = 0; Gg < 4; ++Gg) {
        const int row = Gg * H_ + u;
        const float4* wr = (const float4*)&Wlds[row * I_];
        float c0 = 0.f, c1 = 0.f, c2 = 0.f, c3 = 0.f;
#pragma unroll
        for (int c = 0; c < 16; ++c) {
          float4 w4 = wr[c];
          c0 = fmaf(w4.x, xv[c].x, c0);
          c1 = fmaf(w4.y, xv[c].y, c1);
          c2 = fmaf(w4.z, xv[c].z, c2);
          c3 = fmaf(w4.w, xv[c].w, c3);
        }
        a[Gg] = (c0 + c1) + (c2 + c3) + bias[row];
      }
      uint2 uu;
      uu.x = __builtin_bit_cast(unsigned int, pack2(a[0], a[1]));
      uu.y = __builtin_bit_cast(unsigned int, pack2(a[2], a[3]));
      dstbuf[ps * H_ + u] = uu;
    }
  };

  __syncthreads();   // W_ih/bias staged

  // ---- prologue: produce tile 0 ----
  if (wv >= 1) produce(0, &buf[0][0]);
  __syncthreads();

  for (int tile = 0; tile < NTILES; ++tile) {
    if (wv >= 1) {
      // wave1: flush previous tile's staged y (off the recurrence path)
      if (wv == 1 && tile >= 1) {
        const int tp = tile - 1;
        const int s = j >> 1, o = j & 1;
        const int gt = tp * TS + s - 1;
        float v = ybuf[tp & 1][s][o];
        if (gt >= 0) y[((size_t)gt * B_ + b) * O_ + o] = v;
      }
      // both producers: compute next tile's xg into the other buffer
      if (tile + 1 < NTILES) produce(tile + 1, &buf[(tile + 1) & 1][0]);
    } else {
      const uint2* bp = &buf[tile & 1][0];
#pragma unroll 1
      for (int ch = 0; ch < TS / UNROLL; ++ch) {
        uint2 xr[UNROLL];
#pragma unroll
        for (int k = 0; k < UNROLL; ++k) xr[k] = bp[(ch * UNROLL + k) * H_ + jj];

#pragma unroll
        for (int k = 0; k < UNROLL; ++k) {
          const int s = ch * UNROLL + k;

          int hpi = pack_pair_dpp(hj);
          int hb[18];
#pragma unroll
          for (int t = 0; t < 18; ++t) hb[t] = __builtin_amdgcn_readlane(hpi, 2 * t);

          h2 v0 = __builtin_bit_cast(h2, xr[k].x);
          h2 v1 = __builtin_bit_cast(h2, xr[k].y);
          float a_i0, a_f0, a_g0, a_o0;
          if (j < H_) {
            a_i0 = (float)v0.x; a_f0 = (float)v0.y;
            a_g0 = (float)v1.x; a_o0 = (float)v1.y;
          } else {
            a_i0 = yb; a_f0 = 0.f; a_g0 = 0.f; a_o0 = 0.f;
          }
          float a_i1 = 0.f, a_f1 = 0.f, a_g1 = 0.f, a_o1 = 0.f;
#pragma unroll
          for (int t = 0; t < 18; t += 2) {
            h2 hh0 = __builtin_bit_cast(h2, hb[t]);
            h2 hh1 = __builtin_bit_cast(h2, hb[t + 1]);
            a_i0 = fdot2(wA[t], hh0, a_i0);       a_i1 = fdot2(wA[t + 1], hh1, a_i1);
            a_f0 = fdot2(wA[18 + t], hh0, a_f0);  a_f1 = fdot2(wA[18 + t + 1], hh1, a_f1);
            a_g0 = fdot2(wB[t], hh0, a_g0);       a_g1 = fdot2(wB[t + 1], hh1, a_g1);
            a_o0 = fdot2(wB[18 + t], hh0, a_o0);  a_o1 = fdot2(wB[18 + t + 1], hh1, a_o1);
          }
          float a_i = a_i0 + a_i1;

          if (j < H_) {
            float ig = fsigmoid(a_i);
            float fg = fsigmoid(a_f0 + a_f1);
            float gg = ftanh(a_g0 + a_g1);
            float og = fsigmoid(a_o0 + a_o1);
            cj = fg * cj + ig * gg;
            hj = og * ftanh(cj);
          } else if (j < H_ + O_) {
            ybuf[tile & 1][s][j - H_] = a_i;
          }
        }
      }
    }
    __syncthreads();
  }

  // ---- epilogue ----
  if (wv == 1) {
    // flush last tile's staged y
    const int tp = NTILES - 1;
    const int s = j >> 1, o = j & 1;
    const int gt = tp * TS + s - 1;
    float v = ybuf[tp & 1][s][o];
    if (gt >= 0) y[((size_t)gt * B_ + b) * O_ + o] = v;
  } else if (wv == 0) {
    // last y (t = T-1) directly from final h
    int hpi = pack_pair_dpp(hj);
    float a = yb;
#pragma unroll
    for (int t = 0; t < 18; ++t) {
      h2 hh = __builtin_bit_cast(h2, __builtin_amdgcn_readlane(hpi, 2 * t));
      a = fdot2(wA[t], hh, a);
    }
    if (j == H_ || j == H_ + 1) {
      y[((size_t)(T_ - 1) * B_ + b) * O_ + (j - H_)] = a;
    }
  }
}

extern "C" void kernel_launch(void* const* d_in, const int* in_sizes, int n_in,
                              void* d_out, int out_size, void* d_ws, size_t ws_size,
                              hipStream_t stream) {
  const float* x     = (const float*)d_in[0];
  const float* W_ih  = (const float*)d_in[1];
  const float* W_hh  = (const float*)d_in[2];
  const float* b_ih  = (const float*)d_in[3];
  const float* b_hh  = (const float*)d_in[4];
  const float* W_out = (const float*)d_in[5];
  const float* b_out = (const float*)d_in[6];
  float* y           = (float*)d_out;

  lstm_fused<<<dim3(B_), dim3(192), 0, stream>>>(
      x, W_ih, W_hh, b_ih, b_hh, W_out, b_out, y);
}

// Round 11
// 2285.420 us; speedup vs baseline: 1.1007x; 1.1007x over previous
//
#include <hip/hip_runtime.h>
#include <hip/hip_fp16.h>

#define B_ 256
#define T_ 4096
#define I_ 64
#define H_ 36
#define G_ 144   // 4*H
#define O_ 2
#define TS 32            // timesteps per LDS tile
#define NTILES (T_ / TS) // 128
#define UNROLL 8
#define WSTRIDE 68       // padded W_ih row stride (floats): banks spread, see R11 note

typedef __fp16 h2 __attribute__((ext_vector_type(2)));

__device__ __forceinline__ float fsigmoid(float x) {
  float e = __builtin_amdgcn_exp2f(x * -1.442695040888963f);
  return __builtin_amdgcn_rcpf(1.0f + e);
}
__device__ __forceinline__ float ftanh(float x) {
  float e = __builtin_amdgcn_exp2f(x * 2.885390081777926f);
  return 1.0f - 2.0f * __builtin_amdgcn_rcpf(1.0f + e);
}
__device__ __forceinline__ h2 pack2(float lo, float hi) {
  return __builtin_amdgcn_cvt_pkrtz(lo, hi);
}
__device__ __forceinline__ float fdot2(h2 a, h2 b, float c) {
  return __builtin_amdgcn_fdot2(a, b, c, false);
}

// broadcast helper: build (h[j], h[j+1]) half2 on even lanes, no DS ops.
__device__ __forceinline__ int pack_pair_dpp(float hj) {
  int hn_i = __builtin_amdgcn_update_dpp(0, __float_as_int(hj), 0xF5, 0xF, 0xF, true);
  float hn = __int_as_float(hn_i);
  return __builtin_bit_cast(int, pack2(hj, hn));
}

// ---------------- fully fused LSTM: wave0 = recurrence, waves1-2 = xg gemm + stage ----------------
__global__ __launch_bounds__(192, 1) void lstm_fused(
    const float* __restrict__ x,      // [T][B][64]
    const float* __restrict__ W_ih,   // [144][64]
    const float* __restrict__ W_hh,   // [144][36]
    const float* __restrict__ b_ih,   // [144]
    const float* __restrict__ b_hh,   // [144]
    const float* __restrict__ W_out,  // [2][36]
    const float* __restrict__ b_out,  // [2]
    float* __restrict__ y)            // [T][B][2] fp32
{
  __shared__ float Wlds[G_ * WSTRIDE];  // W_ih fp32, stride-padded: 38.3 KiB
  __shared__ float bias[G_];            // b_ih+b_hh
  __shared__ uint2 buf[2][TS * H_];     // xg tiles, fp16-packed (i,f),(g,o): 18.4 KiB
  __shared__ float ybuf[2][TS][O_];     // staged y pairs

  const int b = blockIdx.x;
  const int tid = threadIdx.x;
  const int wv = tid >> 6;            // 0 = consumer, 1/2 = producers
  const int j = tid & 63;

  // ---- stage W_ih + bias into LDS (all 192 threads), padded stride ----
  {
    const float4* src = (const float4*)W_ih;
    for (int i = tid; i < G_ * I_ / 4; i += 192) {
      int row = i >> 4;              // 16 float4 per source row
      int c4  = i & 15;
      *(float4*)&Wlds[row * WSTRIDE + c4 * 4] = src[i];
    }
    for (int i = tid; i < G_; i += 192) bias[i] = b_ih[i] + b_hh[i];
  }

  // ---- consumer init (wave 0): W_hh / W_out fp16 pairs in registers ----
  h2 wA[36], wB[36];                  // wA[0..17]=i pairs, wA[18..35]=f; wB: g,o
  float hj = 0.0f, cj = 0.0f, yb = 0.0f;
  int jj = 0;
  if (wv == 0) {
    if (j < H_) {
#pragma unroll
      for (int t = 0; t < 18; t++) {
        wA[t]      = pack2(W_hh[j * H_ + 2 * t],            W_hh[j * H_ + 2 * t + 1]);
        wA[18 + t] = pack2(W_hh[(j + H_) * H_ + 2 * t],     W_hh[(j + H_) * H_ + 2 * t + 1]);
        wB[t]      = pack2(W_hh[(j + 2 * H_) * H_ + 2 * t], W_hh[(j + 2 * H_) * H_ + 2 * t + 1]);
        wB[18 + t] = pack2(W_hh[(j + 3 * H_) * H_ + 2 * t], W_hh[(j + 3 * H_) * H_ + 2 * t + 1]);
      }
    } else if (j < H_ + O_) {
      const int o = j - H_;
#pragma unroll
      for (int t = 0; t < 18; t++) {
        wA[t] = pack2(W_out[o * H_ + 2 * t], W_out[o * H_ + 2 * t + 1]);
        wA[18 + t] = pack2(0.f, 0.f);
        wB[t] = pack2(0.f, 0.f); wB[18 + t] = pack2(0.f, 0.f);
      }
      yb = b_out[o];
    } else {
#pragma unroll
      for (int k = 0; k < H_; k++) { wA[k] = pack2(0.f, 0.f); wB[k] = pack2(0.f, 0.f); }
    }
    jj = (j < H_) ? j : 0;
  }

  // ---- producer lane mapping: step = (wv-1)*16 + (lane>>2), quarter = lane&3 ----
  const int ps = ((wv - 1) << 4) + (j >> 2);   // 0..31 (valid for wv>=1)
  const int pq = j & 3;                        // units pq*9 .. pq*9+8

  auto produce = [&](int tt, uint2* dstbuf) {
    const float4* xrow = (const float4*)(x + ((size_t)(tt * TS + ps) * B_ + b) * I_);
    float4 xv[16];
#pragma unroll
    for (int c = 0; c < 16; ++c) xv[c] = xrow[c];
#pragma unroll
    for (int m = 0; m < 9; ++m) {
      const int u = pq * 9 + m;
      float a[4];
#pragma unroll
      for (int Gg = 0; Gg < 4; ++Gg) {
        const int row = Gg * H_ + u;
        const float* wr = &Wlds[row * WSTRIDE];
        float c0 = 0.f, c1 = 0.f, c2 = 0.f, c3 = 0.f;
#pragma unroll
        for (int c = 0; c < 16; ++c) {
          float4 w4 = *(const float4*)&wr[c * 4];
          c0 = fmaf(w4.x, xv[c].x, c0);
          c1 = fmaf(w4.y, xv[c].y, c1);
          c2 = fmaf(w4.z, xv[c].z, c2);
          c3 = fmaf(w4.w, xv[c].w, c3);
        }
        a[Gg] = (c0 + c1) + (c2 + c3) + bias[row];
      }
      uint2 uu;
      uu.x = __builtin_bit_cast(unsigned int, pack2(a[0], a[1]));
      uu.y = __builtin_bit_cast(unsigned int, pack2(a[2], a[3]));
      dstbuf[ps * H_ + u] = uu;
    }
  };

  __syncthreads();   // W_ih/bias staged

  // ---- prologue: produce tile 0 ----
  if (wv >= 1) produce(0, &buf[0][0]);
  __syncthreads();

  for (int tile = 0; tile < NTILES; ++tile) {
    if (wv >= 1) {
      // wave1: flush previous tile's staged y (off the recurrence path)
      if (wv == 1 && tile >= 1) {
        const int tp = tile - 1;
        const int s = j >> 1, o = j & 1;
        const int gt = tp * TS + s - 1;
        float v = ybuf[tp & 1][s][o];
        if (gt >= 0) y[((size_t)gt * B_ + b) * O_ + o] = v;
      }
      // both producers: compute next tile's xg into the other buffer
      if (tile + 1 < NTILES) produce(tile + 1, &buf[(tile + 1) & 1][0]);
    } else {
      const uint2* bp = &buf[tile & 1][0];
#pragma unroll 1
      for (int ch = 0; ch < TS / UNROLL; ++ch) {
        uint2 xr[UNROLL];
#pragma unroll
        for (int k = 0; k < UNROLL; ++k) xr[k] = bp[(ch * UNROLL + k) * H_ + jj];

#pragma unroll
        for (int k = 0; k < UNROLL; ++k) {
          const int s = ch * UNROLL + k;

          int hpi = pack_pair_dpp(hj);
          int hb[18];
#pragma unroll
          for (int t = 0; t < 18; ++t) hb[t] = __builtin_amdgcn_readlane(hpi, 2 * t);

          h2 v0 = __builtin_bit_cast(h2, xr[k].x);
          h2 v1 = __builtin_bit_cast(h2, xr[k].y);
          float a_i0, a_f0, a_g0, a_o0;
          if (j < H_) {
            a_i0 = (float)v0.x; a_f0 = (float)v0.y;
            a_g0 = (float)v1.x; a_o0 = (float)v1.y;
          } else {
            a_i0 = yb; a_f0 = 0.f; a_g0 = 0.f; a_o0 = 0.f;
          }
          float a_i1 = 0.f, a_f1 = 0.f, a_g1 = 0.f, a_o1 = 0.f;
#pragma unroll
          for (int t = 0; t < 18; t += 2) {
            h2 hh0 = __builtin_bit_cast(h2, hb[t]);
            h2 hh1 = __builtin_bit_cast(h2, hb[t + 1]);
            a_i0 = fdot2(wA[t], hh0, a_i0);       a_i1 = fdot2(wA[t + 1], hh1, a_i1);
            a_f0 = fdot2(wA[18 + t], hh0, a_f0);  a_f1 = fdot2(wA[18 + t + 1], hh1, a_f1);
            a_g0 = fdot2(wB[t], hh0, a_g0);       a_g1 = fdot2(wB[t + 1], hh1, a_g1);
            a_o0 = fdot2(wB[18 + t], hh0, a_o0);  a_o1 = fdot2(wB[18 + t + 1], hh1, a_o1);
          }
          float a_i = a_i0 + a_i1;

          if (j < H_) {
            float ig = fsigmoid(a_i);
            float fg = fsigmoid(a_f0 + a_f1);
            float gg = ftanh(a_g0 + a_g1);
            float og = fsigmoid(a_o0 + a_o1);
            cj = fg * cj + ig * gg;
            hj = og * ftanh(cj);
          } else if (j < H_ + O_) {
            ybuf[tile & 1][s][j - H_] = a_i;
          }
        }
      }
    }
    __syncthreads();
  }

  // ---- epilogue ----
  if (wv == 1) {
    // flush last tile's staged y
    const int tp = NTILES - 1;
    const int s = j >> 1, o = j & 1;
    const int gt = tp * TS + s - 1;
    float v = ybuf[tp & 1][s][o];
    if (gt >= 0) y[((size_t)gt * B_ + b) * O_ + o] = v;
  } else if (wv == 0) {
    // last y (t = T-1) directly from final h
    int hpi = pack_pair_dpp(hj);
    float a = yb;
#pragma unroll
    for (int t = 0; t < 18; ++t) {
      h2 hh = __builtin_bit_cast(h2, __builtin_amdgcn_readlane(hpi, 2 * t));
      a = fdot2(wA[t], hh, a);
    }
    if (j == H_ || j == H_ + 1) {
      y[((size_t)(T_ - 1) * B_ + b) * O_ + (j - H_)] = a;
    }
  }
}

extern "C" void kernel_launch(void* const* d_in, const int* in_sizes, int n_in,
                              void* d_out, int out_size, void* d_ws, size_t ws_size,
                              hipStream_t stream) {
  const float* x     = (const float*)d_in[0];
  const float* W_ih  = (const float*)d_in[1];
  const float* W_hh  = (const float*)d_in[2];
  const float* b_ih  = (const float*)d_in[3];
  const float* b_hh  = (const float*)d_in[4];
  const float* W_out = (const float*)d_in[5];
  const float* b_out = (const float*)d_in[6];
  float* y           = (float*)d_out;

  lstm_fused<<<dim3(B_), dim3(192), 0, stream>>>(
      x, W_ih, W_hh, b_ih, b_hh, W_out, b_out, y);
}

// Round 12
// 2239.666 us; speedup vs baseline: 1.1232x; 1.0204x over previous
//
#include <hip/hip_runtime.h>
#include <hip/hip_fp16.h>

#define B_ 256
#define T_ 4096
#define I_ 64
#define H_ 36
#define G_ 144   // 4*H
#define O_ 2
#define TS 32            // timesteps per LDS tile
#define NTILES (T_ / TS) // 128
#define UNROLL 8
#define WSTRIDE 68       // padded W_ih row stride (floats): 4-row reads hit 16 disjoint banks

typedef __fp16 h2 __attribute__((ext_vector_type(2)));

__device__ __forceinline__ float fsigmoid(float x) {
  float e = __builtin_amdgcn_exp2f(x * -1.442695040888963f);
  return __builtin_amdgcn_rcpf(1.0f + e);
}
__device__ __forceinline__ float ftanh(float x) {
  float e = __builtin_amdgcn_exp2f(x * 2.885390081777926f);
  return 1.0f - 2.0f * __builtin_amdgcn_rcpf(1.0f + e);
}
__device__ __forceinline__ h2 pack2(float lo, float hi) {
  return __builtin_amdgcn_cvt_pkrtz(lo, hi);
}
__device__ __forceinline__ float fdot2(h2 a, h2 b, float c) {
  return __builtin_amdgcn_fdot2(a, b, c, false);
}

// broadcast helper: build (h[j], h[j+1]) half2 on even lanes, no DS ops.
__device__ __forceinline__ int pack_pair_dpp(float hj) {
  int hn_i = __builtin_amdgcn_update_dpp(0, __float_as_int(hj), 0xF5, 0xF, 0xF, true);
  float hn = __int_as_float(hn_i);
  return __builtin_bit_cast(int, pack2(hj, hn));
}

// ---------------- fully fused LSTM: wave0 = recurrence, waves1-2 = xg gemm + stage ----------------
__global__ __launch_bounds__(192, 1) void lstm_fused(
    const float* __restrict__ x,      // [T][B][64]
    const float* __restrict__ W_ih,   // [144][64]
    const float* __restrict__ W_hh,   // [144][36]
    const float* __restrict__ b_ih,   // [144]
    const float* __restrict__ b_hh,   // [144]
    const float* __restrict__ W_out,  // [2][36]
    const float* __restrict__ b_out,  // [2]
    float* __restrict__ y)            // [T][B][2] fp32
{
  __shared__ float Wlds[G_ * WSTRIDE];  // W_ih fp32, stride-padded: 38.3 KiB
  __shared__ float bias[G_];            // b_ih+b_hh
  __shared__ uint2 buf[2][TS * H_];     // xg tiles, fp16-packed (i,f),(g,o): 18.4 KiB
  __shared__ float ybuf[2][TS][O_];     // staged y pairs

  const int b = blockIdx.x;
  const int tid = threadIdx.x;
  const int wv = tid >> 6;            // 0 = consumer, 1/2 = producers
  const int j = tid & 63;

  // ---- stage W_ih + bias into LDS (all 192 threads), padded stride ----
  {
    const float4* src = (const float4*)W_ih;
    for (int i = tid; i < G_ * I_ / 4; i += 192) {
      int row = i >> 4;              // 16 float4 per source row
      int c4  = i & 15;
      *(float4*)&Wlds[row * WSTRIDE + c4 * 4] = src[i];
    }
    for (int i = tid; i < G_; i += 192) bias[i] = b_ih[i] + b_hh[i];
  }

  // ---- consumer init (wave 0): W_hh / W_out fp16 pairs in registers ----
  h2 wA[36], wB[36];                  // wA[0..17]=i pairs, wA[18..35]=f; wB: g,o
  float hj = 0.0f, cj = 0.0f, yb = 0.0f;
  int jj = 0;
  if (wv == 0) {
    if (j < H_) {
#pragma unroll
      for (int t = 0; t < 18; t++) {
        wA[t]      = pack2(W_hh[j * H_ + 2 * t],            W_hh[j * H_ + 2 * t + 1]);
        wA[18 + t] = pack2(W_hh[(j + H_) * H_ + 2 * t],     W_hh[(j + H_) * H_ + 2 * t + 1]);
        wB[t]      = pack2(W_hh[(j + 2 * H_) * H_ + 2 * t], W_hh[(j + 2 * H_) * H_ + 2 * t + 1]);
        wB[18 + t] = pack2(W_hh[(j + 3 * H_) * H_ + 2 * t], W_hh[(j + 3 * H_) * H_ + 2 * t + 1]);
      }
    } else if (j < H_ + O_) {
      const int o = j - H_;
#pragma unroll
      for (int t = 0; t < 18; t++) {
        wA[t] = pack2(W_out[o * H_ + 2 * t], W_out[o * H_ + 2 * t + 1]);
        wA[18 + t] = pack2(0.f, 0.f);
        wB[t] = pack2(0.f, 0.f); wB[18 + t] = pack2(0.f, 0.f);
      }
      yb = b_out[o];
    } else {
#pragma unroll
      for (int k = 0; k < H_; k++) { wA[k] = pack2(0.f, 0.f); wB[k] = pack2(0.f, 0.f); }
    }
    jj = (j < H_) ? j : 0;
    __builtin_amdgcn_s_setprio(1);    // favor the recurrence wave in VALU arbitration
  }

  // ---- producer lane mapping: step = (wv-1)*16 + (lane>>2), quarter = lane&3 ----
  const int ps = ((wv - 1) << 4) + (j >> 2);   // 0..31 (valid for wv>=1)
  const int pq = j & 3;                        // units pq*9 .. pq*9+8

  // NOTE: m-loop deliberately ROLLED (#pragma unroll 1) to keep the producer
  // code ~2.5KB; the fully-unrolled version (~20KB) thrashes the shared L1 I$
  // against the consumer's fetch stream (R12 theory).
  auto produce = [&](int tt, uint2* dstbuf) {
    const float4* xrow = (const float4*)(x + ((size_t)(tt * TS + ps) * B_ + b) * I_);
    float4 xv[16];
#pragma unroll
    for (int c = 0; c < 16; ++c) xv[c] = xrow[c];
#pragma unroll 1
    for (int m = 0; m < 9; ++m) {
      const int u = pq * 9 + m;
      float a[4];
#pragma unroll
      for (int Gg = 0; Gg < 4; ++Gg) {
        const int row = Gg * H_ + u;
        const float* wr = &Wlds[row * WSTRIDE];
        float c0 = 0.f, c1 = 0.f, c2 = 0.f, c3 = 0.f;
#pragma unroll
        for (int c = 0; c < 16; ++c) {
          float4 w4 = *(const float4*)&wr[c * 4];
          c0 = fmaf(w4.x, xv[c].x, c0);
          c1 = fmaf(w4.y, xv[c].y, c1);
          c2 = fmaf(w4.z, xv[c].z, c2);
          c3 = fmaf(w4.w, xv[c].w, c3);
        }
        a[Gg] = (c0 + c1) + (c2 + c3) + bias[row];
      }
      uint2 uu;
      uu.x = __builtin_bit_cast(unsigned int, pack2(a[0], a[1]));
      uu.y = __builtin_bit_cast(unsigned int, pack2(a[2], a[3]));
      dstbuf[ps * H_ + u] = uu;
    }
  };

  __syncthreads();   // W_ih/bias staged

  // ---- prologue: produce tile 0 ----
  if (wv >= 1) produce(0, &buf[0][0]);
  __syncthreads();

  for (int tile = 0; tile < NTILES; ++tile) {
    if (wv >= 1) {
      // wave1: flush previous tile's staged y (off the recurrence path)
      if (wv == 1 && tile >= 1) {
        const int tp = tile - 1;
        const int s = j >> 1, o = j & 1;
        const int gt = tp * TS + s - 1;
        float v = ybuf[tp & 1][s][o];
        if (gt >= 0) y[((size_t)gt * B_ + b) * O_ + o] = v;
      }
      // both producers: compute next tile's xg into the other buffer
      if (tile + 1 < NTILES) produce(tile + 1, &buf[(tile + 1) & 1][0]);
    } else {
      const uint2* bp = &buf[tile & 1][0];
#pragma unroll 1
      for (int ch = 0; ch < TS / UNROLL; ++ch) {
        uint2 xr[UNROLL];
#pragma unroll
        for (int k = 0; k < UNROLL; ++k) xr[k] = bp[(ch * UNROLL + k) * H_ + jj];

#pragma unroll
        for (int k = 0; k < UNROLL; ++k) {
          const int s = ch * UNROLL + k;

          int hpi = pack_pair_dpp(hj);
          int hb[18];
#pragma unroll
          for (int t = 0; t < 18; ++t) hb[t] = __builtin_amdgcn_readlane(hpi, 2 * t);

          h2 v0 = __builtin_bit_cast(h2, xr[k].x);
          h2 v1 = __builtin_bit_cast(h2, xr[k].y);
          float a_i0, a_f0, a_g0, a_o0;
          if (j < H_) {
            a_i0 = (float)v0.x; a_f0 = (float)v0.y;
            a_g0 = (float)v1.x; a_o0 = (float)v1.y;
          } else {
            a_i0 = yb; a_f0 = 0.f; a_g0 = 0.f; a_o0 = 0.f;
          }
          float a_i1 = 0.f, a_f1 = 0.f, a_g1 = 0.f, a_o1 = 0.f;
#pragma unroll
          for (int t = 0; t < 18; t += 2) {
            h2 hh0 = __builtin_bit_cast(h2, hb[t]);
            h2 hh1 = __builtin_bit_cast(h2, hb[t + 1]);
            a_i0 = fdot2(wA[t], hh0, a_i0);       a_i1 = fdot2(wA[t + 1], hh1, a_i1);
            a_f0 = fdot2(wA[18 + t], hh0, a_f0);  a_f1 = fdot2(wA[18 + t + 1], hh1, a_f1);
            a_g0 = fdot2(wB[t], hh0, a_g0);       a_g1 = fdot2(wB[t + 1], hh1, a_g1);
            a_o0 = fdot2(wB[18 + t], hh0, a_o0);  a_o1 = fdot2(wB[18 + t + 1], hh1, a_o1);
          }
          float a_i = a_i0 + a_i1;

          if (j < H_) {
            float ig = fsigmoid(a_i);
            float fg = fsigmoid(a_f0 + a_f1);
            float gg = ftanh(a_g0 + a_g1);
            float og = fsigmoid(a_o0 + a_o1);
            cj = fg * cj + ig * gg;
            hj = og * ftanh(cj);
          } else if (j < H_ + O_) {
            ybuf[tile & 1][s][j - H_] = a_i;
          }
        }
      }
    }
    __syncthreads();
  }

  // ---- epilogue ----
  if (wv == 1) {
    // flush last tile's staged y
    const int tp = NTILES - 1;
    const int s = j >> 1, o = j & 1;
    const int gt = tp * TS + s - 1;
    float v = ybuf[tp & 1][s][o];
    if (gt >= 0) y[((size_t)gt * B_ + b) * O_ + o] = v;
  } else if (wv == 0) {
    __builtin_amdgcn_s_setprio(0);
    // last y (t = T-1) directly from final h
    int hpi = pack_pair_dpp(hj);
    float a = yb;
#pragma unroll
    for (int t = 0; t < 18; ++t) {
      h2 hh = __builtin_bit_cast(h2, __builtin_amdgcn_readlane(hpi, 2 * t));
      a = fdot2(wA[t], hh, a);
    }
    if (j == H_ || j == H_ + 1) {
      y[((size_t)(T_ - 1) * B_ + b) * O_ + (j - H_)] = a;
    }
  }
}

extern "C" void kernel_launch(void* const* d_in, const int* in_sizes, int n_in,
                              void* d_out, int out_size, void* d_ws, size_t ws_size,
                              hipStream_t stream) {
  const float* x     = (const float*)d_in[0];
  const float* W_ih  = (const float*)d_in[1];
  const float* W_hh  = (const float*)d_in[2];
  const float* b_ih  = (const float*)d_in[3];
  const float* b_hh  = (const float*)d_in[4];
  const float* W_out = (const float*)d_in[5];
  const float* b_out = (const float*)d_in[6];
  float* y           = (float*)d_out;

  lstm_fused<<<dim3(B_), dim3(192), 0, stream>>>(
      x, W_ih, W_hh, b_ih, b_hh, W_out, b_out, y);
}

// Round 13
// 1264.560 us; speedup vs baseline: 1.9893x; 1.7711x over previous
//
#include <hip/hip_runtime.h>
#include <hip/hip_fp16.h>

#define B_ 256
#define T_ 4096
#define I_ 64
#define H_ 36
#define G_ 144   // 4*H
#define O_ 2
#define TS 32            // timesteps per LDS tile
#define NTILES (T_ / TS) // 128
#define UNROLL 8

typedef __fp16 h2 __attribute__((ext_vector_type(2)));

__device__ __forceinline__ float fsigmoid(float x) {
  float e = __builtin_amdgcn_exp2f(x * -1.442695040888963f);
  return __builtin_amdgcn_rcpf(1.0f + e);
}
__device__ __forceinline__ float ftanh(float x) {
  float e = __builtin_amdgcn_exp2f(x * 2.885390081777926f);
  return 1.0f - 2.0f * __builtin_amdgcn_rcpf(1.0f + e);
}
__device__ __forceinline__ h2 pack2(float lo, float hi) {
  return __builtin_amdgcn_cvt_pkrtz(lo, hi);
}
__device__ __forceinline__ float fdot2(h2 a, h2 b, float c) {
  return __builtin_amdgcn_fdot2(a, b, c, false);
}

// build (v[2k], v[2k+1]) pairs on even lanes via DPP quad_perm [1,1,3,3]; no DS ops.
__device__ __forceinline__ int pack_pair_dpp(float v) {
  int n_i = __builtin_amdgcn_update_dpp(0, __float_as_int(v), 0xF5, 0xF, 0xF, true);
  return __builtin_bit_cast(int, pack2(v, __int_as_float(n_i)));
}

// ---------------- fully fused LSTM ----------------
// wave0  = recurrence (frozen R9 math; xg init from fp32 LDS)
// wave1/2 = xg producers: W_ih rows IN REGISTERS (fp16 pairs), x broadcast via
//           readlane, fp32 ds_write_b32 out. Zero wide LDS reads (R13 theory:
//           R10-12's 4-way-duplicated ds_read_b128 storm was saturating the
//           shared LDS pipe and stalling the consumer).
__global__ __launch_bounds__(192, 1) void lstm_fused(
    const float* __restrict__ x,      // [T][B][64]
    const float* __restrict__ W_ih,   // [144][64]
    const float* __restrict__ W_hh,   // [144][36]
    const float* __restrict__ b_ih,   // [144]
    const float* __restrict__ b_hh,   // [144]
    const float* __restrict__ W_out,  // [2][36]
    const float* __restrict__ b_out,  // [2]
    float* __restrict__ y)            // [T][B][2] fp32
{
  __shared__ float buf[2][TS * G_];   // xg tiles fp32: 36.9 KiB
  __shared__ float ybuf[2][TS][O_];   // staged y pairs

  const int b = blockIdx.x;
  const int tid = threadIdx.x;
  const int wv = tid >> 6;            // 0 = consumer, 1/2 = producers
  const int j = tid & 63;

  // ================= consumer state (wave 0) =================
  h2 wA[36], wB[36];                  // wA[0..17]=i pairs, wA[18..35]=f; wB: g,o
  float hj = 0.0f, cj = 0.0f, yb = 0.0f;
  int jj = 0;

  // ================= producer state (waves 1,2) =================
  h2 wp0[32], wp1[32];                // fp16 pairs of W_ih rows rowA / rowB
  float bias0 = 0.f, bias1 = 0.f;
  int rowA = 0, rowB = 0;
  bool hasB = false;

  if (wv == 0) {
    if (j < H_) {
#pragma unroll
      for (int t = 0; t < 18; t++) {
        wA[t]      = pack2(W_hh[j * H_ + 2 * t],            W_hh[j * H_ + 2 * t + 1]);
        wA[18 + t] = pack2(W_hh[(j + H_) * H_ + 2 * t],     W_hh[(j + H_) * H_ + 2 * t + 1]);
        wB[t]      = pack2(W_hh[(j + 2 * H_) * H_ + 2 * t], W_hh[(j + 2 * H_) * H_ + 2 * t + 1]);
        wB[18 + t] = pack2(W_hh[(j + 3 * H_) * H_ + 2 * t], W_hh[(j + 3 * H_) * H_ + 2 * t + 1]);
      }
    } else if (j < H_ + O_) {
      const int o = j - H_;
#pragma unroll
      for (int t = 0; t < 18; t++) {
        wA[t] = pack2(W_out[o * H_ + 2 * t], W_out[o * H_ + 2 * t + 1]);
        wA[18 + t] = pack2(0.f, 0.f);
        wB[t] = pack2(0.f, 0.f); wB[18 + t] = pack2(0.f, 0.f);
      }
      yb = b_out[o];
    } else {
#pragma unroll
      for (int k = 0; k < H_; k++) { wA[k] = pack2(0.f, 0.f); wB[k] = pack2(0.f, 0.f); }
    }
    jj = (j < H_) ? j : 0;
    __builtin_amdgcn_s_setprio(1);
  } else {
    // rows: wave1 -> 0..71, wave2 -> 72..143 (64 via rowA, 8 via rowB on lanes 0..7)
    const int base = (wv - 1) * 72;
    rowA = base + j;
    hasB = (j < 8);
    rowB = base + 64 + (j & 7);
#pragma unroll
    for (int k = 0; k < 32; k++) {
      wp0[k] = pack2(W_ih[rowA * I_ + 2 * k], W_ih[rowA * I_ + 2 * k + 1]);
      wp1[k] = hasB ? pack2(W_ih[rowB * I_ + 2 * k], W_ih[rowB * I_ + 2 * k + 1])
                    : pack2(0.f, 0.f);
    }
    bias0 = b_ih[rowA] + b_hh[rowA];
    bias1 = hasB ? (b_ih[rowB] + b_hh[rowB]) : 0.f;
  }

  // ---- producer: compute one tile's xg into dst ----
  auto produce = [&](int tt, float* dst) {
    const float* xcol = x + ((size_t)(tt * TS) * B_ + b) * I_ + j;
#pragma unroll 1
    for (int c4 = 0; c4 < TS / 4; ++c4) {
      float xv0 = xcol[(size_t)(c4 * 4 + 0) * (B_ * I_)];
      float xv1 = xcol[(size_t)(c4 * 4 + 1) * (B_ * I_)];
      float xv2 = xcol[(size_t)(c4 * 4 + 2) * (B_ * I_)];
      float xv3 = xcol[(size_t)(c4 * 4 + 3) * (B_ * I_)];
      float xa[4] = {xv0, xv1, xv2, xv3};
#pragma unroll
      for (int u = 0; u < 4; ++u) {
        const int s = c4 * 4 + u;
        int xp = pack_pair_dpp(xa[u]);
        float a0e = bias0, a0o = 0.f, a1e = bias1, a1o = 0.f;
#pragma unroll
        for (int k = 0; k < 32; k += 2) {
          h2 pe = __builtin_bit_cast(h2, __builtin_amdgcn_readlane(xp, 2 * k));
          h2 po = __builtin_bit_cast(h2, __builtin_amdgcn_readlane(xp, 2 * k + 2));
          a0e = fdot2(wp0[k], pe, a0e);
          a0o = fdot2(wp0[k + 1], po, a0o);
          a1e = fdot2(wp1[k], pe, a1e);
          a1o = fdot2(wp1[k + 1], po, a1o);
        }
        dst[s * G_ + rowA] = a0e + a0o;
        if (hasB) dst[s * G_ + rowB] = a1e + a1o;
      }
    }
  };

  // ---- prologue: produce tile 0 ----
  if (wv >= 1) produce(0, &buf[0][0]);
  __syncthreads();

  for (int tile = 0; tile < NTILES; ++tile) {
    if (wv >= 1) {
      // wave1: flush previous tile's staged y (off the recurrence path)
      if (wv == 1 && tile >= 1) {
        const int tp = tile - 1;
        const int s = j >> 1, o = j & 1;
        const int gt = tp * TS + s - 1;
        float v = ybuf[tp & 1][s][o];
        if (gt >= 0) y[((size_t)gt * B_ + b) * O_ + o] = v;
      }
      if (tile + 1 < NTILES) produce(tile + 1, &buf[(tile + 1) & 1][0]);
    } else {
      const float* bp = &buf[tile & 1][0];
#pragma unroll 1
      for (int ch = 0; ch < TS / UNROLL; ++ch) {
        // batch-load the chunk's 4 gate pre-activations per step (fp32)
        float xi[UNROLL], xf[UNROLL], xg_[UNROLL], xo[UNROLL];
#pragma unroll
        for (int k = 0; k < UNROLL; ++k) {
          const int s = ch * UNROLL + k;
          xi[k]  = bp[s * G_ + jj];
          xf[k]  = bp[s * G_ + 36 + jj];
          xg_[k] = bp[s * G_ + 72 + jj];
          xo[k]  = bp[s * G_ + 108 + jj];
        }

#pragma unroll
        for (int k = 0; k < UNROLL; ++k) {
          const int s = ch * UNROLL + k;

          int hpi = pack_pair_dpp(hj);
          int hb[18];
#pragma unroll
          for (int t = 0; t < 18; ++t) hb[t] = __builtin_amdgcn_readlane(hpi, 2 * t);

          float a_i0, a_f0, a_g0, a_o0;
          if (j < H_) {
            a_i0 = xi[k]; a_f0 = xf[k]; a_g0 = xg_[k]; a_o0 = xo[k];
          } else {
            a_i0 = yb; a_f0 = 0.f; a_g0 = 0.f; a_o0 = 0.f;
          }
          float a_i1 = 0.f, a_f1 = 0.f, a_g1 = 0.f, a_o1 = 0.f;
#pragma unroll
          for (int t = 0; t < 18; t += 2) {
            h2 hh0 = __builtin_bit_cast(h2, hb[t]);
            h2 hh1 = __builtin_bit_cast(h2, hb[t + 1]);
            a_i0 = fdot2(wA[t], hh0, a_i0);       a_i1 = fdot2(wA[t + 1], hh1, a_i1);
            a_f0 = fdot2(wA[18 + t], hh0, a_f0);  a_f1 = fdot2(wA[18 + t + 1], hh1, a_f1);
            a_g0 = fdot2(wB[t], hh0, a_g0);       a_g1 = fdot2(wB[t + 1], hh1, a_g1);
            a_o0 = fdot2(wB[18 + t], hh0, a_o0);  a_o1 = fdot2(wB[18 + t + 1], hh1, a_o1);
          }
          float a_i = a_i0 + a_i1;

          if (j < H_) {
            float ig = fsigmoid(a_i);
            float fg = fsigmoid(a_f0 + a_f1);
            float gg = ftanh(a_g0 + a_g1);
            float og = fsigmoid(a_o0 + a_o1);
            cj = fg * cj + ig * gg;
            hj = og * ftanh(cj);
          } else if (j < H_ + O_) {
            ybuf[tile & 1][s][j - H_] = a_i;
          }
        }
      }
    }
    __syncthreads();
  }

  // ---- epilogue ----
  if (wv == 1) {
    const int tp = NTILES - 1;
    const int s = j >> 1, o = j & 1;
    const int gt = tp * TS + s - 1;
    float v = ybuf[tp & 1][s][o];
    if (gt >= 0) y[((size_t)gt * B_ + b) * O_ + o] = v;
  } else if (wv == 0) {
    __builtin_amdgcn_s_setprio(0);
    // last y (t = T-1) directly from final h
    int hpi = pack_pair_dpp(hj);
    float a = yb;
#pragma unroll
    for (int t = 0; t < 18; ++t) {
      h2 hh = __builtin_bit_cast(h2, __builtin_amdgcn_readlane(hpi, 2 * t));
      a = fdot2(wA[t], hh, a);
    }
    if (j == H_ || j == H_ + 1) {
      y[((size_t)(T_ - 1) * B_ + b) * O_ + (j - H_)] = a;
    }
  }
}

extern "C" void kernel_launch(void* const* d_in, const int* in_sizes, int n_in,
                              void* d_out, int out_size, void* d_ws, size_t ws_size,
                              hipStream_t stream) {
  const float* x     = (const float*)d_in[0];
  const float* W_ih  = (const float*)d_in[1];
  const float* W_hh  = (const float*)d_in[2];
  const float* b_ih  = (const float*)d_in[3];
  const float* b_hh  = (const float*)d_in[4];
  const float* W_out = (const float*)d_in[5];
  const float* b_out = (const float*)d_in[6];
  float* y           = (float*)d_out;

  lstm_fused<<<dim3(B_), dim3(192), 0, stream>>>(
      x, W_ih, W_hh, b_ih, b_hh, W_out, b_out, y);
}